// Round 3
// baseline (4063.147 us; speedup 1.0000x reference)
//
#include <hip/hip_runtime.h>

// Problem constants (match reference)
#define FQ 8        // fields
#define NSEQ 2      // sequence fields
#define BQ 4096     // batch
#define LQ 50       // sequence length
#define VQ 100000   // vocab
#define EQ 64       // emb dim (== wavefront size)
#define NPAIR 28    // unordered field pairs
#define CQ 4        // batch elems per block (1 per wave)
#define CHUNKS (BQ / CQ)   // 1024 blocks per pair

// triu_indices(8, k=1) order
__device__ const int PA[NPAIR] = {0,0,0,0,0,0,0, 1,1,1,1,1,1, 2,2,2,2,2, 3,3,3,3, 4,4,4, 5,5, 6};
__device__ const int PB[NPAIR] = {1,2,3,4,5,6,7, 2,3,4,5,6,7, 3,4,5,6,7, 4,5,6,7, 5,6,7, 6,7, 7};

// ---------------- main kernels (R2 verbatim — known-correct, 119.4 us) ----------------
template <bool ATOMIC>
__global__ __launch_bounds__(256) void pair_pool_dot(
    const int* __restrict__ x_seq,
    const int* __restrict__ x_cat,
    const float* __restrict__ tables,
    float* __restrict__ partial,
    float* __restrict__ out)
{
    const int blk   = blockIdx.x;
    const int pair  = blk / CHUNKS;
    const int chunk = blk - pair * CHUNKS;
    const int b0    = chunk * CQ;
    const int a = PA[pair], c = PB[pair];
    const int tid  = threadIdx.x;
    const int lane = tid & 63;
    const int wave = tid >> 6;
    const int b    = b0 + wave;

    __shared__ int sidx[2][CQ][LQ];

    if (a < NSEQ) {
        if (tid < CQ * LQ) {
            int bl = tid / LQ, l = tid - bl * LQ;
            sidx[0][bl][l] = x_seq[((size_t)a * BQ + b0 + bl) * LQ + l];
        }
    }
    if (c < NSEQ) {
        if (tid < CQ * LQ) {
            int bl = tid / LQ, l = tid - bl * LQ;
            sidx[1][bl][l] = x_seq[((size_t)c * BQ + b0 + bl) * LQ + l];
        }
    }
    if (a < NSEQ || c < NSEQ) __syncthreads();

    const float* __restrict__ tab1 = tables + ((size_t)a * FQ + c) * VQ * EQ;
    const float* __restrict__ tab2 = tables + ((size_t)c * FQ + a) * VQ * EQ;

    float va, vc;
    if (a < NSEQ) {
        float acc = 0.0f;
        #pragma unroll 10
        for (int l = 0; l < LQ; ++l)
            acc += tab1[(size_t)sidx[0][wave][l] * EQ + lane];
        va = acc * (1.0f / LQ);
    } else {
        int v = x_cat[(size_t)(a - NSEQ) * BQ + b];
        va = tab1[(size_t)v * EQ + lane];
    }
    if (c < NSEQ) {
        float acc = 0.0f;
        #pragma unroll 10
        for (int l = 0; l < LQ; ++l)
            acc += tab2[(size_t)sidx[1][wave][l] * EQ + lane];
        vc = acc * (1.0f / LQ);
    } else {
        int v = x_cat[(size_t)(c - NSEQ) * BQ + b];
        vc = tab2[(size_t)v * EQ + lane];
    }

    float prod = va * vc;
    #pragma unroll
    for (int off = 32; off; off >>= 1)
        prod += __shfl_down(prod, off, 64);
    if (lane == 0) {
        if (ATOMIC) atomicAdd(&out[b], prod);
        else        partial[(size_t)pair * BQ + b] = prod;
    }
}

__global__ __launch_bounds__(256) void reduce_pairs(
    const float* __restrict__ partial, float* __restrict__ out)
{
    int b = blockIdx.x * 256 + threadIdx.x;
    if (b < BQ) {
        float s = 0.0f;
        #pragma unroll
        for (int p = 0; p < NPAIR; ++p)
            s += partial[(size_t)p * BQ + b];
        out[b] = s;
    }
}

__global__ __launch_bounds__(256) void zero_out(float* __restrict__ out)
{
    int b = blockIdx.x * 256 + threadIdx.x;
    if (b < BQ) out[b] = 0.0f;
}

// ---------------- diagnostic kernels (intentional; enter rocprof top-5) ----------------
// Random 256B-row gathers from `tables`, REPS times over the same 204,800-entry
// index multiset (x_seq field 0).
//   slot_mode==0 (Diag A): fixed table slot 1  -> 22.3 MB unique footprint, max reuse.
//   slot_mode==1 (Diag B): slot=(r*13+5)&63    -> 1.6 GB footprint, no cross-rep reuse.
// Rotation of the index position by r*97 prevents the compiler hoisting the
// rep-invariant gather (addresses differ each rep; multiset identical).
#define DIAG_BLOCKS 2048
#define NIDX (BQ * LQ)     // 204800
#define PER_WAVE (NIDX / (DIAG_BLOCKS * 4))   // 25

__global__ __launch_bounds__(256) void diag_gather(
    const int* __restrict__ idx,      // x_seq (field 0 = first NIDX ints)
    const float* __restrict__ tables, // full [64][V][E]
    float* __restrict__ ws_out,
    int reps, int slot_mode)
{
    const int bl = blockIdx.x;
    const int tid = threadIdx.x;
    const int lane = tid & 63;
    const int wave = tid >> 6;
    const int base = bl * (PER_WAVE * 4) + wave * PER_WAVE;

    float acc = 0.0f;
    for (int r = 0; r < reps; ++r) {
        const int slot = slot_mode ? ((r * 13 + 5) & 63) : 1;
        const float* __restrict__ tab = tables + (size_t)slot * VQ * EQ;
        const int rot = r * 97;
        #pragma unroll 5
        for (int i = 0; i < PER_WAVE; ++i) {
            int pos = base + i + rot;
            if (pos >= NIDX) pos -= NIDX;
            int v = idx[pos];
            acc += tab[(size_t)v * EQ + lane];
        }
    }
    #pragma unroll
    for (int off = 32; off; off >>= 1)
        acc += __shfl_down(acc, off, 64);
    __shared__ float part[4];
    if (lane == 0) part[wave] = acc;
    __syncthreads();
    if (tid == 0) ws_out[bl] = part[0] + part[1] + part[2] + part[3];
}

extern "C" void kernel_launch(void* const* d_in, const int* in_sizes, int n_in,
                              void* d_out, int out_size, void* d_ws, size_t ws_size,
                              hipStream_t stream) {
    const int*   x_seq  = (const int*)d_in[0];
    const int*   x_cat  = (const int*)d_in[1];
    const float* tables = (const float*)d_in[2];
    float*       out    = (float*)d_out;

    const size_t need = (size_t)NPAIR * BQ * sizeof(float);
    if (ws_size >= need) {
        float* partial = (float*)d_ws;
        pair_pool_dot<false><<<NPAIR * CHUNKS, 256, 0, stream>>>(
            x_seq, x_cat, tables, partial, out);
        reduce_pairs<<<(BQ + 255) / 256, 256, 0, stream>>>(partial, out);
    } else {
        zero_out<<<(BQ + 255) / 256, 256, 0, stream>>>(out);
        pair_pool_dot<true><<<NPAIR * CHUNKS, 256, 0, stream>>>(
            x_seq, x_cat, tables, nullptr, out);
    }

    // Diagnostics (write into far end of ws; never read back on device).
    if (ws_size >= need + (size_t)2 * DIAG_BLOCKS * sizeof(float)) {
        float* diag_ws = (float*)((char*)d_ws + ws_size) - 2 * DIAG_BLOCKS;
        // Diag A: max-reuse single table, 400 reps (~21 GB logical).
        diag_gather<<<DIAG_BLOCKS, 256, 0, stream>>>(
            x_seq, tables, diag_ws, 400, 0);
        // Diag B: no-reuse slot rotation, 200 reps (~10.5 GB logical).
        diag_gather<<<DIAG_BLOCKS, 256, 0, stream>>>(
            x_seq, tables, diag_ws + DIAG_BLOCKS, 200, 1);
    }
}

// Round 4
// 1085.626 us; speedup vs baseline: 3.7427x; 3.7427x over previous
//
#include <hip/hip_runtime.h>

// Problem constants (match reference)
#define FQ 8
#define NSEQ 2
#define BQ 4096
#define LQ 50
#define VQ 100000
#define EQ 64
#define NPAIR 28
#define NIDXF (BQ * LQ)        // 204800 incidences per seq field
#define SLAB_ROWS 200
#define NSLAB 500              // 500 * 200 = 100000 = VQ exactly
#define NJOB 13                // seq-source interaction jobs

// ws layout (bytes)
#define WS_ENTRIES 0                         // 2 * 204800 u32 = 1,638,400
#define WS_BASE    1638400                   // 2 * 501 u32 (padded 4096)
#define WS_CURSOR  1642496                   // 2 * 500 u32 (counts, then cursors)
#define WS_PARTIAL 1646592                   // 28 * 4096 f32 = 458,752
#define WS_Q       2105344                   // 13 * 4096 * 64 f32 = 13,631,488
#define WS_NEED    (2105344ULL + (size_t)NJOB * BQ * EQ * 4)

// triu_indices(8, k=1) order
__device__ const int PA[NPAIR] = {0,0,0,0,0,0,0, 1,1,1,1,1,1, 2,2,2,2,2, 3,3,3,3, 4,4,4, 5,5, 6};
__device__ const int PB[NPAIR] = {1,2,3,4,5,6,7, 2,3,4,5,6,7, 3,4,5,6,7, 4,5,6,7, 5,6,7, 6,7, 7};

// Job j: seq field s -> cat/seq target c.  j=0:(0,1); j=1..6:(0,2..7); j=7..12:(1,2..7).
__device__ __forceinline__ int job_s(int j) { return (j < 7) ? 0 : 1; }
__device__ __forceinline__ int job_c(int j) { return (j == 0) ? 1 : ((j < 7) ? j + 1 : j - 5); }
__device__ __forceinline__ int job_pidx(int j) { return (j < 7) ? job_c(j) - 1 : job_c(j) + 5; }

// ---------------- phase 0: zero counts + partial ----------------
__global__ __launch_bounds__(256) void zero_ws(unsigned* __restrict__ cursor,
                                               float* __restrict__ partial)
{
    int i = blockIdx.x * 256 + threadIdx.x;
    int stride = gridDim.x * 256;
    for (int k = i; k < 2 * NSLAB; k += stride) cursor[k] = 0u;
    for (int k = i; k < NPAIR * BQ; k += stride) partial[k] = 0.0f;
}

// ---------------- phase 1: histogram of row-ids into 500 buckets per field ----------------
__global__ __launch_bounds__(256) void hist_kernel(const int* __restrict__ x_seq,
                                                   unsigned* __restrict__ counts)
{
    __shared__ unsigned h[2 * NSLAB];
    for (int k = threadIdx.x; k < 2 * NSLAB; k += 256) h[k] = 0u;
    __syncthreads();
    int i0 = blockIdx.x * 256 + threadIdx.x, stride = gridDim.x * 256;
    for (int i = i0; i < 2 * NIDXF; i += stride) {
        int s = i / NIDXF;
        int v = x_seq[i];
        atomicAdd(&h[s * NSLAB + v / SLAB_ROWS], 1u);
    }
    __syncthreads();
    for (int k = threadIdx.x; k < 2 * NSLAB; k += 256)
        if (h[k]) atomicAdd(&counts[k], h[k]);
}

// ---------------- phase 2: prefix scan -> bucket bases + cursors ----------------
// cnt_cur holds counts on entry; on exit it holds per-bucket write cursors (= exclusive base).
__global__ __launch_bounds__(512) void scan_kernel(unsigned* __restrict__ cnt_cur,
                                                   unsigned* __restrict__ base)
{
    __shared__ unsigned sc[512];
    int tid = threadIdx.x;
    for (int s = 0; s < 2; ++s) {
        unsigned c = (tid < NSLAB) ? cnt_cur[s * NSLAB + tid] : 0u;
        sc[tid] = c;
        __syncthreads();
        for (int off = 1; off < 512; off <<= 1) {
            unsigned val = (tid >= off) ? sc[tid - off] : 0u;
            __syncthreads();
            sc[tid] += val;
            __syncthreads();
        }
        if (tid < NSLAB) {
            unsigned excl = sc[tid] - c;
            base[s * (NSLAB + 1) + tid] = excl;
            cnt_cur[s * NSLAB + tid] = excl;
        }
        if (tid == NSLAB - 1) base[s * (NSLAB + 1) + NSLAB] = sc[tid];
        __syncthreads();
    }
}

// ---------------- phase 3: scatter packed (v,b) entries into buckets ----------------
__global__ __launch_bounds__(256) void scatter_kernel(const int* __restrict__ x_seq,
                                                      unsigned* __restrict__ cursor,
                                                      unsigned* __restrict__ entries)
{
    int i0 = blockIdx.x * 256 + threadIdx.x, stride = gridDim.x * 256;
    for (int i = i0; i < 2 * NIDXF; i += stride) {
        int s = i / NIDXF;
        int r = i - s * NIDXF;
        int v = x_seq[i];
        int b = r / LQ;
        unsigned pos = atomicAdd(&cursor[s * NSLAB + v / SLAB_ROWS], 1u);
        entries[(size_t)s * NIDXF + pos] = ((unsigned)v << 12) | (unsigned)b;
    }
}

// ---------------- phase 4: build partner Q vectors for the 13 jobs ----------------
// j=0: Q = pooled P[1][0] (seq).  j>=1: Q = T_{c->s}[x_cat[c]] (single gather).
__global__ __launch_bounds__(256) void qbuild_kernel(const int* __restrict__ x_seq,
                                                     const int* __restrict__ x_cat,
                                                     const float* __restrict__ tables,
                                                     float* __restrict__ Q)
{
    int job  = blockIdx.x >> 6;
    int blk  = blockIdx.x & 63;
    int lane = threadIdx.x & 63, wave = threadIdx.x >> 6;
    int b0 = blk * 64;
    if (job == 0) {
        const float* __restrict__ tab = tables + (size_t)(1 * FQ + 0) * VQ * EQ;
        for (int k = wave; k < 64; k += 4) {
            int b = b0 + k;
            const int* xs = x_seq + NIDXF + b * LQ;   // field 1
            float acc = 0.0f;
            #pragma unroll 10
            for (int l = 0; l < LQ; ++l)
                acc += tab[(size_t)xs[l] * EQ + lane];
            Q[(size_t)b * EQ + lane] = acc * (1.0f / LQ);
        }
    } else {
        int s = job_s(job), c = job_c(job);
        const float* __restrict__ tab = tables + ((size_t)c * FQ + s) * VQ * EQ;
        for (int k = wave; k < 64; k += 4) {
            int b = b0 + k;
            int v = x_cat[(size_t)(c - 2) * BQ + b];
            Q[((size_t)job * BQ + b) * EQ + lane] = tab[(size_t)v * EQ + lane];
        }
    }
}

// ---------------- phase 5: slab interaction ----------------
// Block = (job, slab). Stream 200 table rows (51.2 KB) into LDS once (nontemporal),
// then for each bucket entry (v,b): out_pair[b] += dot64(slab_row_v, Q[b]) / 50.
// Q (1 MB/job, ~2 live jobs in the resident window) stays L2-hot.
__global__ __launch_bounds__(256) void interact_kernel(const float* __restrict__ tables,
                                                       const float* __restrict__ Q,
                                                       const unsigned* __restrict__ entries,
                                                       const unsigned* __restrict__ base,
                                                       float* __restrict__ partial)
{
    __shared__ float slab[SLAB_ROWS * EQ];   // 51,200 B -> 3 blocks/CU
    int job = blockIdx.x / NSLAB;
    int sl  = blockIdx.x - job * NSLAB;
    int s = job_s(job), c = job_c(job), pidx = job_pidx(job);

    const float* __restrict__ tab =
        tables + ((size_t)s * FQ + c) * VQ * EQ + (size_t)sl * SLAB_ROWS * EQ;
    for (int i = threadIdx.x; i < SLAB_ROWS * EQ; i += 256)
        slab[i] = __builtin_nontemporal_load(tab + i);   // streamed once: keep out of L2
    __syncthreads();

    int lane = threadIdx.x & 63, wave = threadIdx.x >> 6;
    unsigned st = base[s * (NSLAB + 1) + sl];
    unsigned en = base[s * (NSLAB + 1) + sl + 1];
    const unsigned* __restrict__ ent = entries + (size_t)s * NIDXF;
    const float* __restrict__ Qj = Q + (size_t)job * BQ * EQ;

    for (unsigned k = st + wave; k < en; k += 4) {
        unsigned e = ent[k];
        int b = (int)(e & 4095u);
        int v = (int)(e >> 12) - sl * SLAB_ROWS;
        float q = Qj[(size_t)b * EQ + lane];     // L2-hot
        float r = slab[v * EQ + lane];           // 2 lanes/bank: free
        float p = q * r;
        #pragma unroll
        for (int off = 32; off; off >>= 1)
            p += __shfl_down(p, off, 64);
        if (lane == 0)
            atomicAdd(&partial[(size_t)pidx * BQ + b], p * (1.0f / LQ));
    }
}

// ---------------- phase 6: cat-cat pairs (15, multiplicity ~1: direct) ----------------
__global__ __launch_bounds__(256) void catcat_kernel(const int* __restrict__ x_cat,
                                                     const float* __restrict__ tables,
                                                     float* __restrict__ partial)
{
    int p     = 13 + blockIdx.x / (BQ / 4);
    int chunk = blockIdx.x % (BQ / 4);
    int lane = threadIdx.x & 63, wave = threadIdx.x >> 6;
    int b = chunk * 4 + wave;
    int a = PA[p], c = PB[p];
    int va_i = x_cat[(size_t)(a - 2) * BQ + b];
    int vc_i = x_cat[(size_t)(c - 2) * BQ + b];
    float va = tables[((size_t)a * FQ + c) * VQ * EQ + (size_t)va_i * EQ + lane];
    float vc = tables[((size_t)c * FQ + a) * VQ * EQ + (size_t)vc_i * EQ + lane];
    float pr = va * vc;
    #pragma unroll
    for (int off = 32; off; off >>= 1)
        pr += __shfl_down(pr, off, 64);
    if (lane == 0) partial[(size_t)p * BQ + b] = pr;
}

// ---------------- phase 7: final reduce over 28 pairs ----------------
__global__ __launch_bounds__(256) void reduce_pairs(const float* __restrict__ partial,
                                                    float* __restrict__ out)
{
    int b = blockIdx.x * 256 + threadIdx.x;
    if (b < BQ) {
        float sum = 0.0f;
        #pragma unroll
        for (int p = 0; p < NPAIR; ++p)
            sum += partial[(size_t)p * BQ + b];
        out[b] = sum;
    }
}

// ---------------- fallback (R2 path, known-correct) ----------------
__global__ __launch_bounds__(256) void fb_pair_dot(const int* __restrict__ x_seq,
                                                   const int* __restrict__ x_cat,
                                                   const float* __restrict__ tables,
                                                   float* __restrict__ out)
{
    const int pair  = blockIdx.x / (BQ / 4);
    const int chunk = blockIdx.x % (BQ / 4);
    const int b0 = chunk * 4;
    const int a = PA[pair], c = PB[pair];
    const int tid = threadIdx.x, lane = tid & 63, wave = tid >> 6;
    const int b = b0 + wave;
    __shared__ int sidx[2][4][LQ];
    if (a < NSEQ && tid < 4 * LQ) {
        int bl = tid / LQ, l = tid - bl * LQ;
        sidx[0][bl][l] = x_seq[((size_t)a * BQ + b0 + bl) * LQ + l];
    }
    if (c < NSEQ && tid < 4 * LQ) {
        int bl = tid / LQ, l = tid - bl * LQ;
        sidx[1][bl][l] = x_seq[((size_t)c * BQ + b0 + bl) * LQ + l];
    }
    if (a < NSEQ || c < NSEQ) __syncthreads();
    const float* tab1 = tables + ((size_t)a * FQ + c) * VQ * EQ;
    const float* tab2 = tables + ((size_t)c * FQ + a) * VQ * EQ;
    float va, vc;
    if (a < NSEQ) {
        float acc = 0.0f;
        for (int l = 0; l < LQ; ++l) acc += tab1[(size_t)sidx[0][wave][l] * EQ + lane];
        va = acc * (1.0f / LQ);
    } else va = tab1[(size_t)x_cat[(size_t)(a - NSEQ) * BQ + b] * EQ + lane];
    if (c < NSEQ) {
        float acc = 0.0f;
        for (int l = 0; l < LQ; ++l) acc += tab2[(size_t)sidx[1][wave][l] * EQ + lane];
        vc = acc * (1.0f / LQ);
    } else vc = tab2[(size_t)x_cat[(size_t)(c - NSEQ) * BQ + b] * EQ + lane];
    float prod = va * vc;
    #pragma unroll
    for (int off = 32; off; off >>= 1) prod += __shfl_down(prod, off, 64);
    if (lane == 0) atomicAdd(&out[b], prod);
}

__global__ __launch_bounds__(256) void fb_zero(float* __restrict__ out)
{
    int b = blockIdx.x * 256 + threadIdx.x;
    if (b < BQ) out[b] = 0.0f;
}

extern "C" void kernel_launch(void* const* d_in, const int* in_sizes, int n_in,
                              void* d_out, int out_size, void* d_ws, size_t ws_size,
                              hipStream_t stream) {
    const int*   x_seq  = (const int*)d_in[0];
    const int*   x_cat  = (const int*)d_in[1];
    const float* tables = (const float*)d_in[2];
    float*       out    = (float*)d_out;

    if (ws_size >= WS_NEED) {
        unsigned* entries = (unsigned*)((char*)d_ws + WS_ENTRIES);
        unsigned* basep   = (unsigned*)((char*)d_ws + WS_BASE);
        unsigned* cursor  = (unsigned*)((char*)d_ws + WS_CURSOR);
        float*    partial = (float*)   ((char*)d_ws + WS_PARTIAL);
        float*    Q       = (float*)   ((char*)d_ws + WS_Q);

        zero_ws<<<448, 256, 0, stream>>>(cursor, partial);
        hist_kernel<<<1024, 256, 0, stream>>>(x_seq, cursor);
        scan_kernel<<<1, 512, 0, stream>>>(cursor, basep);
        scatter_kernel<<<1024, 256, 0, stream>>>(x_seq, cursor, entries);
        qbuild_kernel<<<NJOB * 64, 256, 0, stream>>>(x_seq, x_cat, tables, Q);
        interact_kernel<<<NJOB * NSLAB, 256, 0, stream>>>(tables, Q, entries, basep, partial);
        catcat_kernel<<<15 * (BQ / 4), 256, 0, stream>>>(x_cat, tables, partial);
        reduce_pairs<<<(BQ + 255) / 256, 256, 0, stream>>>(partial, out);
    } else {
        fb_zero<<<(BQ + 255) / 256, 256, 0, stream>>>(out);
        fb_pair_dot<<<NPAIR * (BQ / 4), 256, 0, stream>>>(x_seq, x_cat, tables, out);
    }
}

// Round 6
// 246.765 us; speedup vs baseline: 16.4656x; 4.3994x over previous
//
#include <hip/hip_runtime.h>

// Problem constants (match reference)
#define FQ 8
#define NSEQ 2
#define BQ 4096
#define LQ 50
#define VQ 100000
#define EQ 64
#define NPAIR 28
#define NIDXF (BQ * LQ)        // 204800 incidences per seq field
#define SLAB_ROWS 200
#define NSLAB 500              // 500 * 200 = 100000 = VQ
#define NJOB 13                // seq-source interaction jobs
#define NCHB 100               // bucketing chunks per field
#define CHUNK 2048             // incidences per chunk (100*2048 = 204800)

typedef float f32x4 __attribute__((ext_vector_type(4)));   // native vector: nontemporal-ok

// ws byte offsets (generously aligned)
#define WS_ENT  0x000000ULL    // 2*204800 u32   = 1,638,400
#define WS_CNT  0x1A0000ULL    // 2*100*500 u32  =   400,000
#define WS_OFF  0x210000ULL    // 2*100*500 u32  =   400,000
#define WS_BASE 0x280000ULL    // 2*501 u32
#define WS_PART 0x290000ULL    // 28*4*4096 f32  = 1,835,008
#define WS_Q    0x450000ULL    // 4096*64 f32    = 1,048,576
#define WS_NEED 0x550000ULL

// triu_indices(8, k=1) order
__device__ const int PA[NPAIR] = {0,0,0,0,0,0,0, 1,1,1,1,1,1, 2,2,2,2,2, 3,3,3,3, 4,4,4, 5,5, 6};
__device__ const int PB[NPAIR] = {1,2,3,4,5,6,7, 2,3,4,5,6,7, 3,4,5,6,7, 4,5,6,7, 5,6,7, 6,7, 7};

// Job j: seq field s -> target c. j=0:(0,1); j=1..6:(0,2..7); j=7..12:(1,2..7).
__device__ __forceinline__ int job_s(int j)    { return (j < 7) ? 0 : 1; }
__device__ __forceinline__ int job_c(int j)    { return (j == 0) ? 1 : ((j < 7) ? j + 1 : j - 5); }
__device__ __forceinline__ int job_pidx(int j) { return (j < 7) ? job_c(j) - 1 : job_c(j) + 5; }

// ---------------- phase 0: zero the partial accumulator ----------------
__global__ __launch_bounds__(256) void zero_part(float* __restrict__ part)
{
    int i = blockIdx.x * 256 + threadIdx.x, stride = gridDim.x * 256;
    for (int k = i; k < NPAIR * 4 * BQ; k += stride) part[k] = 0.0f;
}

// ---------------- phase 1: per-chunk bucket counts (LDS only, plain stores) ----------------
__global__ __launch_bounds__(256) void countk(const int* __restrict__ x_seq,
                                              unsigned* __restrict__ cnt)
{
    __shared__ unsigned h[NSLAB];
    int blk = blockIdx.x;               // 0..199
    int s = blk / NCHB, ch = blk - s * NCHB;
    for (int k = threadIdx.x; k < NSLAB; k += 256) h[k] = 0u;
    __syncthreads();
    int base = s * NIDXF + ch * CHUNK;
    #pragma unroll
    for (int it = 0; it < CHUNK / 256; ++it) {
        int v = x_seq[base + it * 256 + threadIdx.x];
        atomicAdd(&h[v / SLAB_ROWS], 1u);          // LDS atomic: cheap
    }
    __syncthreads();
    unsigned* c = cnt + ((size_t)s * NCHB + ch) * NSLAB;
    for (int k = threadIdx.x; k < NSLAB; k += 256) c[k] = h[k];
}

// ---------------- phase 2: scan -> per-(chunk,bucket) exclusive offsets + bucket bases ----------------
__global__ __launch_bounds__(512) void scank(const unsigned* __restrict__ cnt,
                                             unsigned* __restrict__ off,
                                             unsigned* __restrict__ base)
{
    __shared__ unsigned sc[512];
    int s = blockIdx.x, tid = threadIdx.x;
    unsigned tot = 0u;
    if (tid < NSLAB) {
        const unsigned* c = cnt + (size_t)s * NCHB * NSLAB + tid;
        for (int b = 0; b < NCHB; ++b) tot += c[(size_t)b * NSLAB];
    }
    sc[tid] = tot;
    __syncthreads();
    for (int o = 1; o < 512; o <<= 1) {
        unsigned v = (tid >= o) ? sc[tid - o] : 0u;
        __syncthreads();
        sc[tid] += v;
        __syncthreads();
    }
    if (tid < NSLAB) {
        unsigned run = sc[tid] - tot;
        base[s * (NSLAB + 1) + tid] = run;
        const unsigned* c = cnt + (size_t)s * NCHB * NSLAB + tid;
        unsigned* o = off + (size_t)s * NCHB * NSLAB + tid;
        for (int b = 0; b < NCHB; ++b) { o[(size_t)b * NSLAB] = run; run += c[(size_t)b * NSLAB]; }
    }
    if (tid == NSLAB - 1) base[s * (NSLAB + 1) + NSLAB] = sc[tid];
}

// ---------------- phase 3: scatter packed (v,b) entries (LDS cursors only) ----------------
__global__ __launch_bounds__(256) void scatterk(const int* __restrict__ x_seq,
                                                const unsigned* __restrict__ off,
                                                unsigned* __restrict__ ent)
{
    __shared__ unsigned cur[NSLAB];
    int blk = blockIdx.x;               // 0..199, mirrors countk
    int s = blk / NCHB, ch = blk - s * NCHB;
    const unsigned* o = off + ((size_t)s * NCHB + ch) * NSLAB;
    for (int k = threadIdx.x; k < NSLAB; k += 256) cur[k] = o[k];
    __syncthreads();
    unsigned* e = ent + (size_t)s * NIDXF;
    #pragma unroll
    for (int it = 0; it < CHUNK / 256; ++it) {
        int i = ch * CHUNK + it * 256 + threadIdx.x;   // incidence index in field s
        int v = x_seq[s * NIDXF + i];
        int b = i / LQ;
        unsigned pos = atomicAdd(&cur[v / SLAB_ROWS], 1u);   // LDS atomic
        e[pos] = ((unsigned)v << 12) | (unsigned)b;
    }
}

// ---------------- phase 4: pooled P_10 (Q for job 0). wave per batch elem ----------------
__global__ __launch_bounds__(256) void qbuild(const int* __restrict__ x_seq,
                                              const float* __restrict__ tables,
                                              float* __restrict__ Q)
{
    int lane = threadIdx.x & 63, w = threadIdx.x >> 6;
    int b = blockIdx.x * 4 + w;
    const float* __restrict__ tab = tables + (size_t)(1 * FQ + 0) * VQ * EQ;  // T_{1->0}
    const int* __restrict__ xs = x_seq + NIDXF + b * LQ;                      // field 1
    float acc = 0.0f;
    #pragma unroll 10
    for (int l = 0; l < LQ; ++l)
        acc += tab[(size_t)xs[l] * EQ + lane];
    Q[(size_t)b * EQ + lane] = acc * (1.0f / LQ);
}

// ---------------- phase 5: slab interaction (4-lane groups, float4 dots) ----------------
// Block = (job, slab). Stream 200 rows (51.2 KB) into LDS once (nontemporal, XOR-swizzled
// against the 16-way bank conflict of the group read pattern). Each 4-lane group handles
// one bucket entry: lane sub owns elements [sub*16, sub*16+15]; 2 shfl_xor finish the dot.
__global__ __launch_bounds__(256) void interactk(const float* __restrict__ tables,
                                                 const float* __restrict__ Q,
                                                 const int* __restrict__ x_cat,
                                                 const unsigned* __restrict__ ent,
                                                 const unsigned* __restrict__ base,
                                                 float* __restrict__ part)
{
    __shared__ float slab[SLAB_ROWS * EQ];   // 51,200 B -> 3 blocks/CU
    int job = blockIdx.x / NSLAB, sl = blockIdx.x - job * NSLAB;
    int s = job_s(job), c = job_c(job), pidx = job_pidx(job);

    const float* __restrict__ tab =
        tables + ((size_t)s * FQ + c) * VQ * EQ + (size_t)sl * SLAB_ROWS * EQ;
    for (int t = threadIdx.x; t < SLAB_ROWS * EQ / 4; t += 256) {
        int lw = t * 4;                       // linear word in the slab
        int v = lw >> 6, wd = lw & 63;
        f32x4 val = __builtin_nontemporal_load((const f32x4*)(tab + lw));
        *(f32x4*)&slab[v * EQ + (wd ^ ((v & 7) << 2))] = val;
    }
    __syncthreads();

    int lane = threadIdx.x & 63;
    int w = threadIdx.x >> 6, g = lane >> 2, sub = lane & 3;
    unsigned st = base[s * (NSLAB + 1) + sl];
    unsigned en = base[s * (NSLAB + 1) + sl + 1];
    const unsigned* __restrict__ e = ent + (size_t)s * NIDXF;
    const float* __restrict__ qtab = tables + ((size_t)c * FQ + s) * VQ * EQ;  // T_{c->s}
    const float sc = 1.0f / LQ;

    for (unsigned k = st + w * 16 + g; k < en; k += 64) {
        unsigned ev = e[k];
        int b = (int)(ev & 4095u);
        int v = (int)(ev >> 12) - sl * SLAB_ROWS;
        const f32x4* __restrict__ q;
        if (job == 0) q = (const f32x4*)(Q + (size_t)b * EQ);
        else {
            int vq = x_cat[(size_t)(c - 2) * BQ + b];
            q = (const f32x4*)(qtab + (size_t)vq * EQ);        // 1MB unique/job: L2-hot
        }
        float p = 0.0f;
        #pragma unroll
        for (int j = 0; j < 4; ++j) {
            int ew = sub * 16 + j * 4;
            f32x4 qv = q[ew >> 2];
            f32x4 rv = *(const f32x4*)&slab[v * EQ + (ew ^ ((v & 7) << 2))];
            p += qv.x * rv.x + qv.y * rv.y + qv.z * rv.z + qv.w * rv.w;
        }
        p += __shfl_xor(p, 1, 64);
        p += __shfl_xor(p, 2, 64);
        if (sub == 0)
            atomicAdd(&part[((size_t)pidx * 4 + (sl & 3)) * BQ + b], p * sc);
    }
}

// ---------------- phase 6: cat-cat pairs (15, at unique-byte floor already) ----------------
__global__ __launch_bounds__(256) void catcatk(const int* __restrict__ x_cat,
                                               const float* __restrict__ tables,
                                               float* __restrict__ part)
{
    int p     = 13 + blockIdx.x / (BQ / 4);
    int chunk = blockIdx.x % (BQ / 4);
    int lane = threadIdx.x & 63, w = threadIdx.x >> 6;
    int b = chunk * 4 + w;
    int a = PA[p], c = PB[p];
    int va_i = x_cat[(size_t)(a - 2) * BQ + b];
    int vc_i = x_cat[(size_t)(c - 2) * BQ + b];
    float va = tables[((size_t)a * FQ + c) * VQ * EQ + (size_t)va_i * EQ + lane];
    float vc = tables[((size_t)c * FQ + a) * VQ * EQ + (size_t)vc_i * EQ + lane];
    float pr = va * vc;
    #pragma unroll
    for (int off = 32; off; off >>= 1)
        pr += __shfl_down(pr, off, 64);
    if (lane == 0) part[((size_t)p * 4 + 0) * BQ + b] = pr;
}

// ---------------- phase 7: final reduce ----------------
__global__ __launch_bounds__(256) void reducek(const float* __restrict__ part,
                                               float* __restrict__ out)
{
    int b = blockIdx.x * 256 + threadIdx.x;
    if (b < BQ) {
        float sum = 0.0f;
        #pragma unroll
        for (int q = 0; q < NPAIR * 4; ++q)
            sum += part[(size_t)q * BQ + b];   // coalesced per q
        out[b] = sum;
    }
}

// ---------------- fallback (R2 path, known-correct) ----------------
__global__ __launch_bounds__(256) void fb_pair_dot(const int* __restrict__ x_seq,
                                                   const int* __restrict__ x_cat,
                                                   const float* __restrict__ tables,
                                                   float* __restrict__ out)
{
    const int pair  = blockIdx.x / (BQ / 4);
    const int chunk = blockIdx.x % (BQ / 4);
    const int b0 = chunk * 4;
    const int a = PA[pair], c = PB[pair];
    const int tid = threadIdx.x, lane = tid & 63, wave = tid >> 6;
    const int b = b0 + wave;
    __shared__ int sidx[2][4][LQ];
    if (a < NSEQ && tid < 4 * LQ) {
        int bl = tid / LQ, l = tid - bl * LQ;
        sidx[0][bl][l] = x_seq[((size_t)a * BQ + b0 + bl) * LQ + l];
    }
    if (c < NSEQ && tid < 4 * LQ) {
        int bl = tid / LQ, l = tid - bl * LQ;
        sidx[1][bl][l] = x_seq[((size_t)c * BQ + b0 + bl) * LQ + l];
    }
    if (a < NSEQ || c < NSEQ) __syncthreads();
    const float* tab1 = tables + ((size_t)a * FQ + c) * VQ * EQ;
    const float* tab2 = tables + ((size_t)c * FQ + a) * VQ * EQ;
    float va, vc;
    if (a < NSEQ) {
        float acc = 0.0f;
        for (int l = 0; l < LQ; ++l) acc += tab1[(size_t)sidx[0][wave][l] * EQ + lane];
        va = acc * (1.0f / LQ);
    } else va = tab1[(size_t)x_cat[(size_t)(a - NSEQ) * BQ + b] * EQ + lane];
    if (c < NSEQ) {
        float acc = 0.0f;
        for (int l = 0; l < LQ; ++l) acc += tab2[(size_t)sidx[1][wave][l] * EQ + lane];
        vc = acc * (1.0f / LQ);
    } else vc = tab2[(size_t)x_cat[(size_t)(c - NSEQ) * BQ + b] * EQ + lane];
    float prod = va * vc;
    #pragma unroll
    for (int off = 32; off; off >>= 1) prod += __shfl_down(prod, off, 64);
    if (lane == 0) atomicAdd(&out[b], prod);
}

__global__ __launch_bounds__(256) void fb_zero(float* __restrict__ out)
{
    int b = blockIdx.x * 256 + threadIdx.x;
    if (b < BQ) out[b] = 0.0f;
}

extern "C" void kernel_launch(void* const* d_in, const int* in_sizes, int n_in,
                              void* d_out, int out_size, void* d_ws, size_t ws_size,
                              hipStream_t stream) {
    const int*   x_seq  = (const int*)d_in[0];
    const int*   x_cat  = (const int*)d_in[1];
    const float* tables = (const float*)d_in[2];
    float*       out    = (float*)d_out;

    if (ws_size >= WS_NEED) {
        unsigned* ent  = (unsigned*)((char*)d_ws + WS_ENT);
        unsigned* cnt  = (unsigned*)((char*)d_ws + WS_CNT);
        unsigned* off  = (unsigned*)((char*)d_ws + WS_OFF);
        unsigned* basep= (unsigned*)((char*)d_ws + WS_BASE);
        float*    part = (float*)   ((char*)d_ws + WS_PART);
        float*    Q    = (float*)   ((char*)d_ws + WS_Q);

        zero_part<<<448, 256, 0, stream>>>(part);
        countk  <<<2 * NCHB, 256, 0, stream>>>(x_seq, cnt);
        scank   <<<2, 512, 0, stream>>>(cnt, off, basep);
        scatterk<<<2 * NCHB, 256, 0, stream>>>(x_seq, off, ent);
        qbuild  <<<BQ / 4, 256, 0, stream>>>(x_seq, tables, Q);
        interactk<<<NJOB * NSLAB, 256, 0, stream>>>(tables, Q, x_cat, ent, basep, part);
        catcatk <<<15 * (BQ / 4), 256, 0, stream>>>(x_cat, tables, part);
        reducek <<<(BQ + 255) / 256, 256, 0, stream>>>(part, out);
    } else {
        fb_zero<<<(BQ + 255) / 256, 256, 0, stream>>>(out);
        fb_pair_dot<<<NPAIR * (BQ / 4), 256, 0, stream>>>(x_seq, x_cat, tables, out);
    }
}